// Round 2
// baseline (2687.714 us; speedup 1.0000x reference)
//
#include <hip/hip_runtime.h>

// LightGCN propagation: N=100000 nodes, E=1e6 edges, D=64, 3 layers.
// out = (emb + h1 + h2 + h3) / 4,  h_{l+1} = deg * segsum_dst( (h_l*deg)[src] )
//
// Strategy: keep state PRE-SCALED (hs = h*deg) so the edge-scatter is pure
// gather + atomic (no deg load, no mul). Atomic f32 scatter into hnext;
// fused post-pass does t = hn*deg, acc += t, hs' = t*deg, hn = 0.

#define N_NODES 100000
#define D 64
#define ND4 (N_NODES * D / 4)   // float4 count = 1,600,000

// Layer-0 init: hs = emb*deg (pre-scaled state) and hn = 0, one pass.
__global__ void init_kernel(const float4* __restrict__ emb,
                            const float* __restrict__ deg,
                            float4* __restrict__ hs,
                            float4* __restrict__ hn, int n4) {
    int i = blockIdx.x * blockDim.x + threadIdx.x;
    if (i >= n4) return;
    float dg = deg[i >> 4];          // 16 float4 per 64-float row
    float4 v = emb[i];
    v.x *= dg; v.y *= dg; v.z *= dg; v.w *= dg;
    hs[i] = v;
    hn[i] = make_float4(0.f, 0.f, 0.f, 0.f);
}

// 16 threads per edge; each thread: one float4 of the pre-scaled src row,
// 4 hardware f32 atomic adds into the dst row.
__global__ void scatter_kernel(const float4* __restrict__ hs,
                               const int* __restrict__ src,
                               const int* __restrict__ dst,
                               float* __restrict__ hnext, int nedges) {
    int tid = blockIdx.x * blockDim.x + threadIdx.x;
    int e = tid >> 4;
    if (e >= nedges) return;
    int d4 = tid & 15;
    int s = src[e];
    int t = dst[e];
    float4 v = hs[s * 16 + d4];
    float* out = hnext + (size_t)t * D + d4 * 4;
    unsafeAtomicAdd(out + 0, v.x);
    unsafeAtomicAdd(out + 1, v.y);
    unsafeAtomicAdd(out + 2, v.z);
    unsafeAtomicAdd(out + 3, v.w);
}

// t = hn*deg ; acc_out = (acc_in + t)*scale ; hs_out = t*deg (if !last) ; hn = 0
__global__ void post_kernel(float4* __restrict__ hn,
                            const float* __restrict__ deg,
                            const float4* __restrict__ acc_in,
                            float4* __restrict__ acc_out,
                            float4* __restrict__ hs_out,
                            int write_hs, float scale, int n4) {
    int i = blockIdx.x * blockDim.x + threadIdx.x;
    if (i >= n4) return;
    float dg = deg[i >> 4];
    float4 t = hn[i];
    t.x *= dg; t.y *= dg; t.z *= dg; t.w *= dg;
    float4 a = acc_in[i];
    a.x = (a.x + t.x) * scale;
    a.y = (a.y + t.y) * scale;
    a.z = (a.z + t.z) * scale;
    a.w = (a.w + t.w) * scale;
    acc_out[i] = a;
    if (write_hs) {
        t.x *= dg; t.y *= dg; t.z *= dg; t.w *= dg;  // pre-scale for next gather
        hs_out[i] = t;
    }
    hn[i] = make_float4(0.f, 0.f, 0.f, 0.f);  // ready for next layer
}

extern "C" void kernel_launch(void* const* d_in, const int* in_sizes, int n_in,
                              void* d_out, int out_size, void* d_ws, size_t ws_size,
                              hipStream_t stream) {
    const float* emb = (const float*)d_in[0];
    const float* deg = (const float*)d_in[1];
    const int*   src = (const int*)d_in[2];
    const int*   dst = (const int*)d_in[3];
    // d_in[4] = n_layers (device scalar): unreadable host-side under graph
    // capture; reference fixes N_LAYERS=3 — hard-coded below.
    float* out  = (float*)d_out;
    float* hs   = (float*)d_ws;                      // N*D floats (pre-scaled h)
    float* hn   = hs + (size_t)N_NODES * D;          // N*D floats (atomic target)

    int nedges = in_sizes[2];

    init_kernel<<<(ND4 + 255) / 256, 256, 0, stream>>>(
        (const float4*)emb, deg, (float4*)hs, (float4*)hn, ND4);

    const float* acc = emb;   // ego embedding (layer 0)
    for (int layer = 0; layer < 3; ++layer) {
        int nthreads = nedges * 16;
        scatter_kernel<<<(nthreads + 255) / 256, 256, 0, stream>>>(
            (const float4*)hs, src, dst, hn, nedges);
        bool last = (layer == 2);
        post_kernel<<<(ND4 + 255) / 256, 256, 0, stream>>>(
            (float4*)hn, deg, (const float4*)acc, (float4*)out, (float4*)hs,
            last ? 0 : 1, last ? 0.25f : 1.0f, ND4);
        acc = out;
    }
}

// Round 3
// 355.087 us; speedup vs baseline: 7.5692x; 7.5692x over previous
//
#include <hip/hip_runtime.h>

// LightGCN propagation: N=100000 nodes, E=1e6 edges, D=64, 3 layers.
// out = (emb + h1 + h2 + h3) / 4,  h_{l+1} = deg * segsum_dst( (h_l*deg)[src] )
//
// R2 insight: atomic scatter wrote 1.0 GB/layer through L2 (WRITE_SIZE),
// 851us/layer, VALUBusy 0.8% -> atomic-write-through bound.
// Fix: device-built dst-sorted CSR (counting sort, once per call), then
// gather-based segment sum: each output element written exactly once.

#define N_NODES 100000
#define D 64
#define ND4 (N_NODES * D / 4)    // 1,600,000 float4
#define SCAN_B 1024
#define NTILES ((N_NODES + SCAN_B - 1) / SCAN_B)   // 98

__global__ void zero_cnt_kernel(int* __restrict__ cnt, int n) {
    int i = blockIdx.x * blockDim.x + threadIdx.x;
    if (i < n) cnt[i] = 0;
}

// hs_a = emb * deg (pre-scaled layer-0 state)
__global__ void init_kernel(const float4* __restrict__ emb,
                            const float* __restrict__ deg,
                            float4* __restrict__ hs, int n4) {
    int i = blockIdx.x * blockDim.x + threadIdx.x;
    if (i >= n4) return;
    float dg = deg[i >> 4];
    float4 v = emb[i];
    v.x *= dg; v.y *= dg; v.z *= dg; v.w *= dg;
    hs[i] = v;
}

__global__ void hist_kernel(const int* __restrict__ dst, int* __restrict__ cnt,
                            int nedges) {
    int e = blockIdx.x * blockDim.x + threadIdx.x;
    if (e < nedges) atomicAdd(&cnt[dst[e]], 1);
}

// Per-tile exclusive scan; tile totals out. Hillis-Steele in LDS.
__global__ void scanA_kernel(const int* __restrict__ cnt, int* __restrict__ off,
                             int* __restrict__ tsum, int n) {
    __shared__ int sm[SCAN_B];
    int t = threadIdx.x;
    int i = blockIdx.x * SCAN_B + t;
    int x = (i < n) ? cnt[i] : 0;
    sm[t] = x;
    __syncthreads();
    for (int o = 1; o < SCAN_B; o <<= 1) {
        int v = (t >= o) ? sm[t - o] : 0;
        __syncthreads();
        sm[t] += v;
        __syncthreads();
    }
    if (i < n) off[i] = sm[t] - x;                 // exclusive
    if (t == SCAN_B - 1) tsum[blockIdx.x] = sm[t]; // tile total
}

// Exclusive scan of tile totals (NTILES <= 1024), in-place.
__global__ void scanB_kernel(int* __restrict__ tsum, int ntiles) {
    __shared__ int sm[SCAN_B];
    int t = threadIdx.x;
    int x = (t < ntiles) ? tsum[t] : 0;
    sm[t] = x;
    __syncthreads();
    for (int o = 1; o < SCAN_B; o <<= 1) {
        int v = (t >= o) ? sm[t - o] : 0;
        __syncthreads();
        sm[t] += v;
        __syncthreads();
    }
    if (t < ntiles) tsum[t] = sm[t] - x;
}

// Add tile bases; duplicate into cursor; thread 0 writes off[N] = E.
__global__ void scanC_kernel(int* __restrict__ off, const int* __restrict__ tsum,
                             int* __restrict__ cursor, int n, int nedges) {
    int i = blockIdx.x * blockDim.x + threadIdx.x;
    if (i >= n) return;
    int v = off[i] + tsum[i >> 10];
    off[i] = v;
    cursor[i] = v;
    if (i == 0) off[n] = nedges;
}

// Place each edge's src into its dst-segment slot.
__global__ void reorder_kernel(const int* __restrict__ src,
                               const int* __restrict__ dst,
                               int* __restrict__ cursor,
                               int* __restrict__ ssrc, int nedges) {
    int e = blockIdx.x * blockDim.x + threadIdx.x;
    if (e >= nedges) return;
    int d = dst[e];
    int p = atomicAdd(&cursor[d], 1);
    ssrc[p] = src[e];
}

// Gather-based segment sum + fused epilogue.
// 16 lanes per node, one float4 per lane. sum = sum_{j} hs_in[ssrc[j]];
// t = sum*deg; acc_out = (acc_in + t)*scale; hs_out = t*deg (next layer).
__global__ void aggregate_kernel(const float4* __restrict__ hs_in,
                                 const int* __restrict__ off,
                                 const int* __restrict__ ssrc,
                                 const float* __restrict__ deg,
                                 const float4* __restrict__ acc_in,
                                 float4* __restrict__ acc_out,
                                 float4* __restrict__ hs_out,
                                 int write_hs, float scale) {
    int tid = blockIdx.x * blockDim.x + threadIdx.x;
    int n = tid >> 4;
    if (n >= N_NODES) return;
    int d4 = tid & 15;
    int start = off[n];
    int end = off[n + 1];
    float4 sum = make_float4(0.f, 0.f, 0.f, 0.f);
    for (int j = start; j < end; ++j) {
        int s = ssrc[j];
        float4 v = hs_in[s * 16 + d4];
        sum.x += v.x; sum.y += v.y; sum.z += v.z; sum.w += v.w;
    }
    float dg = deg[n];
    float4 t;
    t.x = sum.x * dg; t.y = sum.y * dg; t.z = sum.z * dg; t.w = sum.w * dg;
    float4 a = acc_in[tid];
    a.x = (a.x + t.x) * scale;
    a.y = (a.y + t.y) * scale;
    a.z = (a.z + t.z) * scale;
    a.w = (a.w + t.w) * scale;
    acc_out[tid] = a;
    if (write_hs) {
        t.x *= dg; t.y *= dg; t.z *= dg; t.w *= dg;  // pre-scale for next gather
        hs_out[tid] = t;
    }
}

extern "C" void kernel_launch(void* const* d_in, const int* in_sizes, int n_in,
                              void* d_out, int out_size, void* d_ws, size_t ws_size,
                              hipStream_t stream) {
    const float* emb = (const float*)d_in[0];
    const float* deg = (const float*)d_in[1];
    const int*   src = (const int*)d_in[2];
    const int*   dst = (const int*)d_in[3];
    // d_in[4] = n_layers (device scalar, graph-capture unreadable); ref = 3.
    float* out = (float*)d_out;
    int nedges = in_sizes[2];

    // Workspace layout (~56.5 MB)
    float* hs_a   = (float*)d_ws;                         // N*D
    float* hs_b   = hs_a + (size_t)N_NODES * D;           // N*D
    int*   ssrc   = (int*)(hs_b + (size_t)N_NODES * D);   // E
    int*   cnt    = ssrc + nedges;                        // N
    int*   off    = cnt + N_NODES;                        // N+1
    int*   cursor = off + N_NODES + 1;                    // N
    int*   tsum   = cursor + N_NODES;                     // NTILES

    // --- build CSR (once per call; ws re-poisoned every call) ---
    zero_cnt_kernel<<<(N_NODES + 255) / 256, 256, 0, stream>>>(cnt, N_NODES);
    init_kernel<<<(ND4 + 255) / 256, 256, 0, stream>>>(
        (const float4*)emb, deg, (float4*)hs_a, ND4);
    hist_kernel<<<(nedges + 255) / 256, 256, 0, stream>>>(dst, cnt, nedges);
    scanA_kernel<<<NTILES, SCAN_B, 0, stream>>>(cnt, off, tsum, N_NODES);
    scanB_kernel<<<1, SCAN_B, 0, stream>>>(tsum, NTILES);
    scanC_kernel<<<(N_NODES + 255) / 256, 256, 0, stream>>>(
        off, tsum, cursor, N_NODES, nedges);
    reorder_kernel<<<(nedges + 255) / 256, 256, 0, stream>>>(
        src, dst, cursor, ssrc, nedges);

    // --- 3 layers, gather aggregation, fused epilogue ---
    int nthreads = N_NODES * 16;
    int grid = (nthreads + 255) / 256;
    // layer 0: hs_a -> hs_b, acc emb -> out
    aggregate_kernel<<<grid, 256, 0, stream>>>(
        (const float4*)hs_a, off, ssrc, deg, (const float4*)emb,
        (float4*)out, (float4*)hs_b, 1, 1.0f);
    // layer 1: hs_b -> hs_a, acc out -> out
    aggregate_kernel<<<grid, 256, 0, stream>>>(
        (const float4*)hs_b, off, ssrc, deg, (const float4*)out,
        (float4*)out, (float4*)hs_a, 1, 1.0f);
    // layer 2: hs_a -> (none), acc out -> out, final /4
    aggregate_kernel<<<grid, 256, 0, stream>>>(
        (const float4*)hs_a, off, ssrc, deg, (const float4*)out,
        (float4*)out, (float4*)hs_b, 0, 0.25f);
}

// Round 5
// 332.995 us; speedup vs baseline: 8.0713x; 1.0663x over previous
//
#include <hip/hip_runtime.h>
#include <hip/hip_fp16.h>

// LightGCN propagation: N=100000 nodes, E=1e6 edges, D=64, 3 layers.
// out = (emb + h1 + h2 + h3) / 4,  h_{l+1} = deg * segsum_dst( (h_l*deg)[src] )
//
// R3 insight: aggregate gather (256 MB/layer from L3) dominates at ~3.7 TB/s.
// R4 change (resubmit, unmeasured due to GPU timeout): propagated state hs
// stored in FP16 (accumulate fp32) -> gather bytes halve. acc path stays fp32.
// Reorder unchanged (~72us, scatter-bound) - next target if fp16 validates.

#define N_NODES 100000
#define D 64
#define ND4 (N_NODES * D / 4)    // 1,600,000 float4 (acc path)
#define SCAN_B 1024
#define NTILES ((N_NODES + SCAN_B - 1) / SCAN_B)   // 98

union H4 { uint2 u; __half2 h[2]; };   // 4 halves = 8 bytes

__global__ void zero_cnt_kernel(int* __restrict__ cnt, int n) {
    int i = blockIdx.x * blockDim.x + threadIdx.x;
    if (i < n) cnt[i] = 0;
}

// hs_a = fp16(emb * deg)  (pre-scaled layer-0 state)
__global__ void init_kernel(const float4* __restrict__ emb,
                            const float* __restrict__ deg,
                            uint2* __restrict__ hs, int n4) {
    int i = blockIdx.x * blockDim.x + threadIdx.x;
    if (i >= n4) return;
    float dg = deg[i >> 4];          // 16 chunks of 4 dims per 64-dim row
    float4 v = emb[i];
    H4 x;
    x.h[0] = __float22half2_rn(make_float2(v.x * dg, v.y * dg));
    x.h[1] = __float22half2_rn(make_float2(v.z * dg, v.w * dg));
    hs[i] = x.u;
}

__global__ void hist_kernel(const int* __restrict__ dst, int* __restrict__ cnt,
                            int nedges) {
    int e = blockIdx.x * blockDim.x + threadIdx.x;
    if (e < nedges) atomicAdd(&cnt[dst[e]], 1);
}

// Per-tile exclusive scan; tile totals out. Hillis-Steele in LDS.
__global__ void scanA_kernel(const int* __restrict__ cnt, int* __restrict__ off,
                             int* __restrict__ tsum, int n) {
    __shared__ int sm[SCAN_B];
    int t = threadIdx.x;
    int i = blockIdx.x * SCAN_B + t;
    int x = (i < n) ? cnt[i] : 0;
    sm[t] = x;
    __syncthreads();
    for (int o = 1; o < SCAN_B; o <<= 1) {
        int v = (t >= o) ? sm[t - o] : 0;
        __syncthreads();
        sm[t] += v;
        __syncthreads();
    }
    if (i < n) off[i] = sm[t] - x;                 // exclusive
    if (t == SCAN_B - 1) tsum[blockIdx.x] = sm[t]; // tile total
}

// Exclusive scan of tile totals (NTILES <= 1024), in-place.
__global__ void scanB_kernel(int* __restrict__ tsum, int ntiles) {
    __shared__ int sm[SCAN_B];
    int t = threadIdx.x;
    int x = (t < ntiles) ? tsum[t] : 0;
    sm[t] = x;
    __syncthreads();
    for (int o = 1; o < SCAN_B; o <<= 1) {
        int v = (t >= o) ? sm[t - o] : 0;
        __syncthreads();
        sm[t] += v;
        __syncthreads();
    }
    if (t < ntiles) tsum[t] = sm[t] - x;
}

// Add tile bases; duplicate into cursor; thread 0 writes off[N] = E.
__global__ void scanC_kernel(int* __restrict__ off, const int* __restrict__ tsum,
                             int* __restrict__ cursor, int n, int nedges) {
    int i = blockIdx.x * blockDim.x + threadIdx.x;
    if (i >= n) return;
    int v = off[i] + tsum[i >> 10];
    off[i] = v;
    cursor[i] = v;
    if (i == 0) off[n] = nedges;
}

// Place each edge's src into its dst-segment slot.
__global__ void reorder_kernel(const int* __restrict__ src,
                               const int* __restrict__ dst,
                               int* __restrict__ cursor,
                               int* __restrict__ ssrc, int nedges) {
    int e = blockIdx.x * blockDim.x + threadIdx.x;
    if (e >= nedges) return;
    int d = dst[e];
    int p = atomicAdd(&cursor[d], 1);
    ssrc[p] = src[e];
}

// Gather-based segment sum (fp16 state, fp32 accumulate) + fused epilogue.
// 16 lanes per node, 4 dims (8 B fp16) per lane.
// sum = sum_j hs_in[ssrc[j]]; t = sum*deg; acc_out = (acc_in + t)*scale;
// hs_out = fp16(t*deg) for the next layer's gather.
__global__ void aggregate_kernel(const uint2* __restrict__ hs_in,
                                 const int* __restrict__ off,
                                 const int* __restrict__ ssrc,
                                 const float* __restrict__ deg,
                                 const float4* __restrict__ acc_in,
                                 float4* __restrict__ acc_out,
                                 uint2* __restrict__ hs_out,
                                 int write_hs, float scale) {
    int tid = blockIdx.x * blockDim.x + threadIdx.x;
    int n = tid >> 4;
    if (n >= N_NODES) return;
    int d4 = tid & 15;
    int start = off[n];
    int end = off[n + 1];
    float4 sum = make_float4(0.f, 0.f, 0.f, 0.f);
    for (int j = start; j < end; ++j) {
        int s = ssrc[j];
        H4 x;
        x.u = hs_in[s * 16 + d4];
        float2 lo = __half22float2(x.h[0]);
        float2 hi = __half22float2(x.h[1]);
        sum.x += lo.x; sum.y += lo.y; sum.z += hi.x; sum.w += hi.y;
    }
    float dg = deg[n];
    float4 t;
    t.x = sum.x * dg; t.y = sum.y * dg; t.z = sum.z * dg; t.w = sum.w * dg;
    float4 a = acc_in[tid];
    a.x = (a.x + t.x) * scale;
    a.y = (a.y + t.y) * scale;
    a.z = (a.z + t.z) * scale;
    a.w = (a.w + t.w) * scale;
    acc_out[tid] = a;
    if (write_hs) {
        // pre-scale for next layer's gather: hs' = t * deg
        H4 o;
        o.h[0] = __float22half2_rn(make_float2(t.x * dg, t.y * dg));
        o.h[1] = __float22half2_rn(make_float2(t.z * dg, t.w * dg));
        hs_out[tid] = o.u;
    }
}

extern "C" void kernel_launch(void* const* d_in, const int* in_sizes, int n_in,
                              void* d_out, int out_size, void* d_ws, size_t ws_size,
                              hipStream_t stream) {
    const float* emb = (const float*)d_in[0];
    const float* deg = (const float*)d_in[1];
    const int*   src = (const int*)d_in[2];
    const int*   dst = (const int*)d_in[3];
    // d_in[4] = n_layers (device scalar, graph-capture unreadable); ref = 3.
    float* out = (float*)d_out;
    int nedges = in_sizes[2];

    // Workspace layout: hs_a, hs_b are N*D halves (12.8 MB each), then ints.
    __half* hs_a = (__half*)d_ws;                          // N*D halves
    __half* hs_b = hs_a + (size_t)N_NODES * D;             // N*D halves
    int*   ssrc   = (int*)(hs_b + (size_t)N_NODES * D);    // E
    int*   cnt    = ssrc + nedges;                         // N
    int*   off    = cnt + N_NODES;                         // N+1
    int*   cursor = off + N_NODES + 1;                     // N
    int*   tsum   = cursor + N_NODES;                      // NTILES

    // --- build CSR (once per call; ws re-poisoned every call) ---
    zero_cnt_kernel<<<(N_NODES + 255) / 256, 256, 0, stream>>>(cnt, N_NODES);
    init_kernel<<<(ND4 + 255) / 256, 256, 0, stream>>>(
        (const float4*)emb, deg, (uint2*)hs_a, ND4);
    hist_kernel<<<(nedges + 255) / 256, 256, 0, stream>>>(dst, cnt, nedges);
    scanA_kernel<<<NTILES, SCAN_B, 0, stream>>>(cnt, off, tsum, N_NODES);
    scanB_kernel<<<1, SCAN_B, 0, stream>>>(tsum, NTILES);
    scanC_kernel<<<(N_NODES + 255) / 256, 256, 0, stream>>>(
        off, tsum, cursor, N_NODES, nedges);
    reorder_kernel<<<(nedges + 255) / 256, 256, 0, stream>>>(
        src, dst, cursor, ssrc, nedges);

    // --- 3 layers, gather aggregation, fused epilogue ---
    int nthreads = N_NODES * 16;
    int grid = (nthreads + 255) / 256;
    // layer 0: hs_a -> hs_b, acc emb -> out
    aggregate_kernel<<<grid, 256, 0, stream>>>(
        (const uint2*)hs_a, off, ssrc, deg, (const float4*)emb,
        (float4*)out, (uint2*)hs_b, 1, 1.0f);
    // layer 1: hs_b -> hs_a, acc out -> out
    aggregate_kernel<<<grid, 256, 0, stream>>>(
        (const uint2*)hs_b, off, ssrc, deg, (const float4*)out,
        (float4*)out, (uint2*)hs_a, 1, 1.0f);
    // layer 2: hs_a -> (none), acc out -> out, final /4
    aggregate_kernel<<<grid, 256, 0, stream>>>(
        (const uint2*)hs_a, off, ssrc, deg, (const float4*)out,
        (float4*)out, (uint2*)hs_b, 0, 0.25f);
}

// Round 6
// 278.773 us; speedup vs baseline: 9.6412x; 1.1945x over previous
//
#include <hip/hip_runtime.h>
#include <hip/hip_fp16.h>

// LightGCN propagation: N=100000 nodes, E=1e6 edges, D=64, 3 layers.
// out = (emb + h1 + h2 + h3) / 4,  h_{l+1} = deg * segsum_dst( (h_l*deg)[src] )
//
// R5 insight: fp16 halved gather bytes but aggregate barely improved ->
// latency-bound, not L3-BW-bound (serial dependent gather chain + max-of-4
// degree divergence). R6: 8 lanes/node (uint4=16B fp16 loads, 8 nodes/wave)
// + 4x edge-loop unroll (4-deep gather MLP).

#define N_NODES 100000
#define D 64
#define ND4 (N_NODES * D / 4)    // 1,600,000 float4 (acc path)
#define SCAN_B 1024
#define NTILES ((N_NODES + SCAN_B - 1) / SCAN_B)   // 98

union H4 { uint2 u; __half2 h[2]; };   // 4 halves = 8 bytes
union H8 { uint4 u; __half2 h[4]; };   // 8 halves = 16 bytes

__global__ void zero_cnt_kernel(int* __restrict__ cnt, int n) {
    int i = blockIdx.x * blockDim.x + threadIdx.x;
    if (i < n) cnt[i] = 0;
}

// hs_a = fp16(emb * deg)  (pre-scaled layer-0 state)
__global__ void init_kernel(const float4* __restrict__ emb,
                            const float* __restrict__ deg,
                            uint2* __restrict__ hs, int n4) {
    int i = blockIdx.x * blockDim.x + threadIdx.x;
    if (i >= n4) return;
    float dg = deg[i >> 4];          // 16 chunks of 4 dims per 64-dim row
    float4 v = emb[i];
    H4 x;
    x.h[0] = __float22half2_rn(make_float2(v.x * dg, v.y * dg));
    x.h[1] = __float22half2_rn(make_float2(v.z * dg, v.w * dg));
    hs[i] = x.u;
}

__global__ void hist_kernel(const int* __restrict__ dst, int* __restrict__ cnt,
                            int nedges) {
    int e = blockIdx.x * blockDim.x + threadIdx.x;
    if (e < nedges) atomicAdd(&cnt[dst[e]], 1);
}

// Per-tile exclusive scan; tile totals out. Hillis-Steele in LDS.
__global__ void scanA_kernel(const int* __restrict__ cnt, int* __restrict__ off,
                             int* __restrict__ tsum, int n) {
    __shared__ int sm[SCAN_B];
    int t = threadIdx.x;
    int i = blockIdx.x * SCAN_B + t;
    int x = (i < n) ? cnt[i] : 0;
    sm[t] = x;
    __syncthreads();
    for (int o = 1; o < SCAN_B; o <<= 1) {
        int v = (t >= o) ? sm[t - o] : 0;
        __syncthreads();
        sm[t] += v;
        __syncthreads();
    }
    if (i < n) off[i] = sm[t] - x;                 // exclusive
    if (t == SCAN_B - 1) tsum[blockIdx.x] = sm[t]; // tile total
}

// Exclusive scan of tile totals (NTILES <= 1024), in-place.
__global__ void scanB_kernel(int* __restrict__ tsum, int ntiles) {
    __shared__ int sm[SCAN_B];
    int t = threadIdx.x;
    int x = (t < ntiles) ? tsum[t] : 0;
    sm[t] = x;
    __syncthreads();
    for (int o = 1; o < SCAN_B; o <<= 1) {
        int v = (t >= o) ? sm[t - o] : 0;
        __syncthreads();
        sm[t] += v;
        __syncthreads();
    }
    if (t < ntiles) tsum[t] = sm[t] - x;
}

// Add tile bases; duplicate into cursor; thread 0 writes off[N] = E.
__global__ void scanC_kernel(int* __restrict__ off, const int* __restrict__ tsum,
                             int* __restrict__ cursor, int n, int nedges) {
    int i = blockIdx.x * blockDim.x + threadIdx.x;
    if (i >= n) return;
    int v = off[i] + tsum[i >> 10];
    off[i] = v;
    cursor[i] = v;
    if (i == 0) off[n] = nedges;
}

// Place each edge's src into its dst-segment slot.
__global__ void reorder_kernel(const int* __restrict__ src,
                               const int* __restrict__ dst,
                               int* __restrict__ cursor,
                               int* __restrict__ ssrc, int nedges) {
    int e = blockIdx.x * blockDim.x + threadIdx.x;
    if (e >= nedges) return;
    int d = dst[e];
    int p = atomicAdd(&cursor[d], 1);
    ssrc[p] = src[e];
}

__device__ __forceinline__ void acc_h8(float* s, uint4 u) {
    H8 x; x.u = u;
    #pragma unroll
    for (int k = 0; k < 4; ++k) {
        float2 f = __half22float2(x.h[k]);
        s[2 * k]     += f.x;
        s[2 * k + 1] += f.y;
    }
}

// Gather-based segment sum (fp16 state, fp32 accumulate) + fused epilogue.
// 8 lanes per node, 8 dims (16 B fp16) per lane; edge loop unrolled x4 for
// 4-deep gather MLP. sum = sum_j hs_in[ssrc[j]]; t = sum*deg;
// acc_out = (acc_in + t)*scale; hs_out = fp16(t*deg).
__global__ void aggregate_kernel(const uint4* __restrict__ hs_in,
                                 const int* __restrict__ off,
                                 const int* __restrict__ ssrc,
                                 const float* __restrict__ deg,
                                 const float4* __restrict__ acc_in,
                                 float4* __restrict__ acc_out,
                                 uint4* __restrict__ hs_out,
                                 int write_hs, float scale) {
    int tid = blockIdx.x * blockDim.x + threadIdx.x;
    int n = tid >> 3;
    if (n >= N_NODES) return;
    int d8 = tid & 7;                 // 16B chunk (8 dims) of the 64-dim row
    int start = off[n];
    int end = off[n + 1];
    float s[8] = {0.f, 0.f, 0.f, 0.f, 0.f, 0.f, 0.f, 0.f};

    int j = start;
    for (; j + 4 <= end; j += 4) {
        int ia = ssrc[j];
        int ib = ssrc[j + 1];
        int ic = ssrc[j + 2];
        int id = ssrc[j + 3];
        uint4 va = hs_in[ia * 8 + d8];   // 4 independent gathers in flight
        uint4 vb = hs_in[ib * 8 + d8];
        uint4 vc = hs_in[ic * 8 + d8];
        uint4 vd = hs_in[id * 8 + d8];
        acc_h8(s, va);
        acc_h8(s, vb);
        acc_h8(s, vc);
        acc_h8(s, vd);
    }
    for (; j < end; ++j) {
        acc_h8(s, hs_in[ssrc[j] * 8 + d8]);
    }

    float dg = deg[n];
    float t[8];
    #pragma unroll
    for (int k = 0; k < 8; ++k) t[k] = s[k] * dg;

    // acc path: this lane owns float4 indices base, base+1
    int base = n * 16 + d8 * 2;
    float4 a0 = acc_in[base];
    float4 a1 = acc_in[base + 1];
    a0.x = (a0.x + t[0]) * scale;
    a0.y = (a0.y + t[1]) * scale;
    a0.z = (a0.z + t[2]) * scale;
    a0.w = (a0.w + t[3]) * scale;
    a1.x = (a1.x + t[4]) * scale;
    a1.y = (a1.y + t[5]) * scale;
    a1.z = (a1.z + t[6]) * scale;
    a1.w = (a1.w + t[7]) * scale;
    acc_out[base] = a0;
    acc_out[base + 1] = a1;

    if (write_hs) {
        H8 o;
        #pragma unroll
        for (int k = 0; k < 4; ++k)
            o.h[k] = __float22half2_rn(
                make_float2(t[2 * k] * dg, t[2 * k + 1] * dg));
        hs_out[tid] = o.u;   // tid == n*8 + d8
    }
}

extern "C" void kernel_launch(void* const* d_in, const int* in_sizes, int n_in,
                              void* d_out, int out_size, void* d_ws, size_t ws_size,
                              hipStream_t stream) {
    const float* emb = (const float*)d_in[0];
    const float* deg = (const float*)d_in[1];
    const int*   src = (const int*)d_in[2];
    const int*   dst = (const int*)d_in[3];
    // d_in[4] = n_layers (device scalar, graph-capture unreadable); ref = 3.
    float* out = (float*)d_out;
    int nedges = in_sizes[2];

    // Workspace layout: hs_a, hs_b are N*D halves (12.8 MB each), then ints.
    __half* hs_a = (__half*)d_ws;                          // N*D halves
    __half* hs_b = hs_a + (size_t)N_NODES * D;             // N*D halves
    int*   ssrc   = (int*)(hs_b + (size_t)N_NODES * D);    // E
    int*   cnt    = ssrc + nedges;                         // N
    int*   off    = cnt + N_NODES;                         // N+1
    int*   cursor = off + N_NODES + 1;                     // N
    int*   tsum   = cursor + N_NODES;                      // NTILES

    // --- build CSR (once per call; ws re-poisoned every call) ---
    zero_cnt_kernel<<<(N_NODES + 255) / 256, 256, 0, stream>>>(cnt, N_NODES);
    init_kernel<<<(ND4 + 255) / 256, 256, 0, stream>>>(
        (const float4*)emb, deg, (uint2*)hs_a, ND4);
    hist_kernel<<<(nedges + 255) / 256, 256, 0, stream>>>(dst, cnt, nedges);
    scanA_kernel<<<NTILES, SCAN_B, 0, stream>>>(cnt, off, tsum, N_NODES);
    scanB_kernel<<<1, SCAN_B, 0, stream>>>(tsum, NTILES);
    scanC_kernel<<<(N_NODES + 255) / 256, 256, 0, stream>>>(
        off, tsum, cursor, N_NODES, nedges);
    reorder_kernel<<<(nedges + 255) / 256, 256, 0, stream>>>(
        src, dst, cursor, ssrc, nedges);

    // --- 3 layers, gather aggregation, fused epilogue ---
    int nthreads = N_NODES * 8;
    int grid = (nthreads + 255) / 256;
    // layer 0: hs_a -> hs_b, acc emb -> out
    aggregate_kernel<<<grid, 256, 0, stream>>>(
        (const uint4*)hs_a, off, ssrc, deg, (const float4*)emb,
        (float4*)out, (uint4*)hs_b, 1, 1.0f);
    // layer 1: hs_b -> hs_a, acc out -> out
    aggregate_kernel<<<grid, 256, 0, stream>>>(
        (const uint4*)hs_b, off, ssrc, deg, (const float4*)out,
        (float4*)out, (uint4*)hs_a, 1, 1.0f);
    // layer 2: hs_a -> (none), acc out -> out, final /4
    aggregate_kernel<<<grid, 256, 0, stream>>>(
        (const uint4*)hs_a, off, ssrc, deg, (const float4*)out,
        (float4*)out, (uint4*)hs_b, 0, 0.25f);
}

// Round 9
// 259.153 us; speedup vs baseline: 10.3712x; 1.0757x over previous
//
#include <hip/hip_runtime.h>
#include <hip/hip_fp16.h>

// LightGCN propagation: N=100000 nodes, E=1e6 edges, D=64, 3 layers.
// out = (emb + h1 + h2 + h3) / 4,  h_{l+1} = deg * segsum_dst( (h_l*deg)[src] )
//
// R6 insight: reorder (72us) writes 69.5 MB for a 4 MB payload: scattered 4B
// stores dirty 64B lines across all 8 non-coherent XCD L2s -> partial-line
// writebacks. R8 (2nd resubmit, GPU timeouts): slice-filtered reorder
// (blockIdx&7 -> dst slice) localizes each contiguous ssrc region to one XCD.

#define N_NODES 100000
#define D 64
#define ND4 (N_NODES * D / 4)    // 1,600,000 float4 (acc path)
#define SCAN_B 1024
#define NTILES ((N_NODES + SCAN_B - 1) / SCAN_B)   // 98
#define NSLICE 8
#define SLICE_DIV 12500          // ceil(N_NODES / NSLICE)

union H4 { uint2 u; __half2 h[2]; };   // 4 halves = 8 bytes
union H8 { uint4 u; __half2 h[4]; };   // 8 halves = 16 bytes

// hs_a = fp16(emb * deg) (pre-scaled layer-0 state); also zeroes cnt.
__global__ void init_kernel(const float4* __restrict__ emb,
                            const float* __restrict__ deg,
                            uint2* __restrict__ hs,
                            int* __restrict__ cnt, int n4) {
    int i = blockIdx.x * blockDim.x + threadIdx.x;
    if (i < N_NODES) cnt[i] = 0;
    if (i >= n4) return;
    float dg = deg[i >> 4];          // 16 chunks of 4 dims per 64-dim row
    float4 v = emb[i];
    H4 x;
    x.h[0] = __float22half2_rn(make_float2(v.x * dg, v.y * dg));
    x.h[1] = __float22half2_rn(make_float2(v.z * dg, v.w * dg));
    hs[i] = x.u;
}

__global__ void hist_kernel(const int* __restrict__ dst, int* __restrict__ cnt,
                            int nedges) {
    int e = blockIdx.x * blockDim.x + threadIdx.x;
    if (e < nedges) atomicAdd(&cnt[dst[e]], 1);
}

// Per-tile exclusive scan; tile totals out. Hillis-Steele in LDS.
__global__ void scanA_kernel(const int* __restrict__ cnt, int* __restrict__ off,
                             int* __restrict__ tsum, int n) {
    __shared__ int sm[SCAN_B];
    int t = threadIdx.x;
    int i = blockIdx.x * SCAN_B + t;
    int x = (i < n) ? cnt[i] : 0;
    sm[t] = x;
    __syncthreads();
    for (int o = 1; o < SCAN_B; o <<= 1) {
        int v = (t >= o) ? sm[t - o] : 0;
        __syncthreads();
        sm[t] += v;
        __syncthreads();
    }
    if (i < n) off[i] = sm[t] - x;                 // exclusive
    if (t == SCAN_B - 1) tsum[blockIdx.x] = sm[t]; // tile total
}

// Exclusive scan of tile totals (NTILES <= 1024), in-place.
__global__ void scanB_kernel(int* __restrict__ tsum, int ntiles) {
    __shared__ int sm[SCAN_B];
    int t = threadIdx.x;
    int x = (t < ntiles) ? tsum[t] : 0;
    sm[t] = x;
    __syncthreads();
    for (int o = 1; o < SCAN_B; o <<= 1) {
        int v = (t >= o) ? sm[t - o] : 0;
        __syncthreads();
        sm[t] += v;
        __syncthreads();
    }
    if (t < ntiles) tsum[t] = sm[t] - x;
}

// Add tile bases; duplicate into cursor; thread 0 writes off[N] = E.
__global__ void scanC_kernel(int* __restrict__ off, const int* __restrict__ tsum,
                             int* __restrict__ cursor, int n, int nedges) {
    int i = blockIdx.x * blockDim.x + threadIdx.x;
    if (i >= n) return;
    int v = off[i] + tsum[i >> 10];
    off[i] = v;
    cursor[i] = v;
    if (i == 0) off[n] = nedges;
}

// Slice-filtered scatter: block (chunk = blockIdx>>3, slice = blockIdx&7)
// handles only edges with dst in its slice. ssrc is dst-ordered, so each
// slice's stores land in one contiguous ~E/8 region -> one XCD's L2 owns
// those lines (blockIdx&7 round-robins XCDs), lines fill before eviction.
__global__ void reorder_kernel(const int* __restrict__ src,
                               const int* __restrict__ dst,
                               int* __restrict__ cursor,
                               int* __restrict__ ssrc, int nedges) {
    int slice = blockIdx.x & (NSLICE - 1);
    int e = (blockIdx.x >> 3) * blockDim.x + threadIdx.x;
    if (e >= nedges) return;
    int d = dst[e];
    if (d / SLICE_DIV != slice) return;
    int p = atomicAdd(&cursor[d], 1);
    ssrc[p] = src[e];
}

__device__ __forceinline__ void acc_h8(float* s, uint4 u) {
    H8 x; x.u = u;
    #pragma unroll
    for (int k = 0; k < 4; ++k) {
        float2 f = __half22float2(x.h[k]);
        s[2 * k]     += f.x;
        s[2 * k + 1] += f.y;
    }
}

// Gather-based segment sum (fp16 state, fp32 accumulate) + fused epilogue.
// 8 lanes per node, 8 dims (16 B fp16) per lane; edge loop unrolled x4.
__global__ void aggregate_kernel(const uint4* __restrict__ hs_in,
                                 const int* __restrict__ off,
                                 const int* __restrict__ ssrc,
                                 const float* __restrict__ deg,
                                 const float4* __restrict__ acc_in,
                                 float4* __restrict__ acc_out,
                                 uint4* __restrict__ hs_out,
                                 int write_hs, float scale) {
    int tid = blockIdx.x * blockDim.x + threadIdx.x;
    int n = tid >> 3;
    if (n >= N_NODES) return;
    int d8 = tid & 7;                 // 16B chunk (8 dims) of the 64-dim row
    int start = off[n];
    int end = off[n + 1];
    float s[8] = {0.f, 0.f, 0.f, 0.f, 0.f, 0.f, 0.f, 0.f};

    int j = start;
    for (; j + 4 <= end; j += 4) {
        int ia = ssrc[j];
        int ib = ssrc[j + 1];
        int ic = ssrc[j + 2];
        int id = ssrc[j + 3];
        uint4 va = hs_in[ia * 8 + d8];   // 4 independent gathers in flight
        uint4 vb = hs_in[ib * 8 + d8];
        uint4 vc = hs_in[ic * 8 + d8];
        uint4 vd = hs_in[id * 8 + d8];
        acc_h8(s, va);
        acc_h8(s, vb);
        acc_h8(s, vc);
        acc_h8(s, vd);
    }
    for (; j < end; ++j) {
        acc_h8(s, hs_in[ssrc[j] * 8 + d8]);
    }

    float dg = deg[n];
    float t[8];
    #pragma unroll
    for (int k = 0; k < 8; ++k) t[k] = s[k] * dg;

    // acc path: this lane owns float4 indices base, base+1
    int base = n * 16 + d8 * 2;
    float4 a0 = acc_in[base];
    float4 a1 = acc_in[base + 1];
    a0.x = (a0.x + t[0]) * scale;
    a0.y = (a0.y + t[1]) * scale;
    a0.z = (a0.z + t[2]) * scale;
    a0.w = (a0.w + t[3]) * scale;
    a1.x = (a1.x + t[4]) * scale;
    a1.y = (a1.y + t[5]) * scale;
    a1.z = (a1.z + t[6]) * scale;
    a1.w = (a1.w + t[7]) * scale;
    acc_out[base] = a0;
    acc_out[base + 1] = a1;

    if (write_hs) {
        H8 o;
        #pragma unroll
        for (int k = 0; k < 4; ++k)
            o.h[k] = __float22half2_rn(
                make_float2(t[2 * k] * dg, t[2 * k + 1] * dg));
        hs_out[tid] = o.u;   // tid == n*8 + d8
    }
}

extern "C" void kernel_launch(void* const* d_in, const int* in_sizes, int n_in,
                              void* d_out, int out_size, void* d_ws, size_t ws_size,
                              hipStream_t stream) {
    const float* emb = (const float*)d_in[0];
    const float* deg = (const float*)d_in[1];
    const int*   src = (const int*)d_in[2];
    const int*   dst = (const int*)d_in[3];
    // d_in[4] = n_layers (device scalar, graph-capture unreadable); ref = 3.
    float* out = (float*)d_out;
    int nedges = in_sizes[2];

    // Workspace layout: hs_a, hs_b are N*D halves (12.8 MB each), then ints.
    __half* hs_a = (__half*)d_ws;                          // N*D halves
    __half* hs_b = hs_a + (size_t)N_NODES * D;             // N*D halves
    int*   ssrc   = (int*)(hs_b + (size_t)N_NODES * D);    // E
    int*   cnt    = ssrc + nedges;                         // N
    int*   off    = cnt + N_NODES;                         // N+1
    int*   cursor = off + N_NODES + 1;                     // N
    int*   tsum   = cursor + N_NODES;                      // NTILES

    // --- build CSR (once per call; ws re-poisoned every call) ---
    init_kernel<<<(ND4 + 255) / 256, 256, 0, stream>>>(
        (const float4*)emb, deg, (uint2*)hs_a, cnt, ND4);
    hist_kernel<<<(nedges + 255) / 256, 256, 0, stream>>>(dst, cnt, nedges);
    scanA_kernel<<<NTILES, SCAN_B, 0, stream>>>(cnt, off, tsum, N_NODES);
    scanB_kernel<<<1, SCAN_B, 0, stream>>>(tsum, NTILES);
    scanC_kernel<<<(N_NODES + 255) / 256, 256, 0, stream>>>(
        off, tsum, cursor, N_NODES, nedges);
    reorder_kernel<<<NSLICE * ((nedges + 255) / 256), 256, 0, stream>>>(
        src, dst, cursor, ssrc, nedges);

    // --- 3 layers, gather aggregation, fused epilogue ---
    int nthreads = N_NODES * 8;
    int grid = (nthreads + 255) / 256;
    // layer 0: hs_a -> hs_b, acc emb -> out
    aggregate_kernel<<<grid, 256, 0, stream>>>(
        (const uint4*)hs_a, off, ssrc, deg, (const float4*)emb,
        (float4*)out, (uint4*)hs_b, 1, 1.0f);
    // layer 1: hs_b -> hs_a, acc out -> out
    aggregate_kernel<<<grid, 256, 0, stream>>>(
        (const uint4*)hs_b, off, ssrc, deg, (const float4*)out,
        (float4*)out, (uint4*)hs_a, 1, 1.0f);
    // layer 2: hs_a -> (none), acc out -> out, final /4
    aggregate_kernel<<<grid, 256, 0, stream>>>(
        (const uint4*)hs_a, off, ssrc, deg, (const float4*)out,
        (float4*)out, (uint4*)hs_b, 0, 0.25f);
}